// Round 10
// baseline (390.320 us; speedup 1.0000x reference)
//
#include <hip/hip_runtime.h>

typedef _Float16 h2 __attribute__((ext_vector_type(2)));

__device__ __forceinline__ float frcp(float x){ return __builtin_amdgcn_rcpf(x); }
__device__ __forceinline__ float fexp2(float x){ return __builtin_amdgcn_exp2f(x); }
// tanh(x) = 1 - 2/(e^{2x}+1)
__device__ __forceinline__ float tanh_(float x){ return 1.f - 2.f*frcp(1.f + fexp2(2.8853900817779268f*x)); }

#if __has_builtin(__builtin_amdgcn_fdot2)
#define FDOT2(a,b,c) __builtin_amdgcn_fdot2((a),(b),(c),false)
#else
#define FDOT2(a,b,c) ((c) + (float)(a).x*(float)(b).x + (float)(a).y*(float)(b).y)
#endif

__device__ __forceinline__ float dotu4(uint4 wv, uint4 hv, float acc){
    acc = FDOT2(__builtin_bit_cast(h2, wv.x), __builtin_bit_cast(h2, hv.x), acc);
    acc = FDOT2(__builtin_bit_cast(h2, wv.y), __builtin_bit_cast(h2, hv.y), acc);
    acc = FDOT2(__builtin_bit_cast(h2, wv.z), __builtin_bit_cast(h2, hv.z), acc);
    acc = FDOT2(__builtin_bit_cast(h2, wv.w), __builtin_bit_cast(h2, hv.w), acc);
    return acc;
}

// ---------------- embedding gather + concat -> x[b*128+t][128] fp32 ----------------
__global__ __launch_bounds__(256) void embed_kernel(
    const int* __restrict__ widx, const int* __restrict__ pidx,
    const float* __restrict__ wemb, const float* __restrict__ temb,
    float* __restrict__ x)
{
    int gid = blockIdx.x*256 + threadIdx.x;   // 262144 total
    int bt = gid >> 7, c = gid & 127;
    float v;
    if (c < 100) v = wemb[(size_t)widx[bt]*100 + c];
    else         v = temb[(size_t)pidx[bt]*28 + (c-100)];
    x[gid] = v;
}

// ---------------- pack w_hh (both layers, both dirs) to f16, quarter-k thread layout -------
// Thread t of lstm: q=t&3 (k in [32q,32q+32)), gc=(t>>2)&3 (0=i,1=cell,2=f,3=o), rp=t>>4.
// wpk[L][d][t][j]: j = row*16 + kp (row 0..3 = pytorch rows G*128+4rp+row), uint =
// (f16 w[32q+2kp], f16 w[32q+2kp+1]). G = {0,2,1,3}[gc].
__global__ __launch_bounds__(256) void pack_kernel(
    const float* __restrict__ w0f, const float* __restrict__ w0b,
    const float* __restrict__ w1f, const float* __restrict__ w1b,
    unsigned* __restrict__ wpk0, unsigned* __restrict__ wpk1)
{
    int id = blockIdx.x*256 + threadIdx.x;    // 131072 total
    int L = id >> 16, d = (id >> 15) & 1, t = (id >> 6) & 511, j = id & 63;
    const float* whh = L ? (d ? w1b : w1f) : (d ? w0b : w0f);
    unsigned* dst = L ? wpk1 : wpk0;
    int q = t & 3, gc = (t >> 2) & 3, rp = t >> 4;
    int G = (gc == 0) ? 0 : (gc == 1) ? 2 : (gc == 2) ? 1 : 3;
    int row = j >> 4, kp = j & 15;
    const float* src = whh + (size_t)(G*128 + 4*rp + row)*128 + 32*q + 2*kp;
    unsigned short a = __builtin_bit_cast(unsigned short, (_Float16)src[0]);
    unsigned short b = __builtin_bit_cast(unsigned short, (_Float16)src[1]);
    dst[((size_t)d*512 + t)*64 + j] = (unsigned)a | ((unsigned)b << 16);
}

// ---------------- generic C[m][n] = sum_k A[m][k]*B[n][k] (+biases) (opt exp(2x)) --------
// M fixed 2048 (grid.x=16, BM=128). grid.z selects B/bias/C set. BN=64, BK=16.
// permflag: output column p holds gate-row gr(p) = (p&3)*128 + (p>>2) (for LSTM layout).
// As columns swizzled g(m)=m+4*(m>>5) (round 7: 4-way -> 2-way bank spread).
__global__ __launch_bounds__(256) void gemm_kernel(
    const float* __restrict__ A, int K,
    const float* __restrict__ B0, const float* __restrict__ B1, int ldb,
    const float* __restrict__ bias0a, const float* __restrict__ bias0b,
    const float* __restrict__ bias1a, const float* __restrict__ bias1b,
    float* __restrict__ C0, float* __restrict__ C1, int ldc, int N,
    int expflag, int permflag)
{
    __shared__ float As[16][140];   // [k][g(m)], g(m)=m+4*(m>>5), max 139
    __shared__ float Bs[16][68];    // [k][n]
    const int z = blockIdx.z;
    const float* B  = z ? B1 : B0;
    const float* ba = z ? bias1a : bias0a;
    const float* bb = z ? bias1b : bias0b;
    float* C = z ? C1 : C0;
    const int m0 = blockIdx.x * 128;
    const int n0 = blockIdx.y * 64;
    const int tx = threadIdx.x;
    const int tm = tx & 15, tn = tx >> 4;       // 8x4 micro-tile
    const int arow = tx >> 1, akq = (tx & 1) * 8;
    const int brow = tx >> 2, bkq = (tx & 3) * 4;
    const int g_arow = arow + 4*(arow >> 5);
    const int rbase = tm*8 + 4*(tm >> 2);       // = g(tm*8)
    float acc[8][4];
    #pragma unroll
    for (int r=0;r<8;++r){
        #pragma unroll
        for (int c=0;c<4;++c) acc[r][c]=0.f; }
    const int bn = n0 + brow;
    const int brow_src = permflag ? ((bn & 3)*128 + (bn >> 2)) : bn;
    for (int k0 = 0; k0 < K; k0 += 16) {
        const float* ap = A + (size_t)(m0+arow)*K + k0 + akq;
        float4 a0 = *(const float4*)ap;
        float4 a1 = *(const float4*)(ap+4);
        float4 bv = make_float4(0.f,0.f,0.f,0.f);
        if (bn < N) {
            const float* bp = B + (size_t)brow_src*ldb + k0 + bkq;
            bv = *(const float4*)bp;
        }
        __syncthreads();
        As[akq+0][g_arow]=a0.x; As[akq+1][g_arow]=a0.y; As[akq+2][g_arow]=a0.z; As[akq+3][g_arow]=a0.w;
        As[akq+4][g_arow]=a1.x; As[akq+5][g_arow]=a1.y; As[akq+6][g_arow]=a1.z; As[akq+7][g_arow]=a1.w;
        Bs[bkq+0][brow]=bv.x; Bs[bkq+1][brow]=bv.y; Bs[bkq+2][brow]=bv.z; Bs[bkq+3][brow]=bv.w;
        __syncthreads();
        #pragma unroll
        for (int kk = 0; kk < 16; ++kk) {
            float4 av0 = *(const float4*)&As[kk][rbase];
            float4 av1 = *(const float4*)&As[kk][rbase+4];
            float4 bvv = *(const float4*)&Bs[kk][tn*4];
            float a[8] = {av0.x,av0.y,av0.z,av0.w,av1.x,av1.y,av1.z,av1.w};
            float b[4] = {bvv.x,bvv.y,bvv.z,bvv.w};
            #pragma unroll
            for (int r=0;r<8;++r){
                #pragma unroll
                for (int c=0;c<4;++c)
                    acc[r][c] = fmaf(a[r], b[c], acc[r][c]);
            }
        }
    }
    float bias[4];
    #pragma unroll
    for (int c=0;c<4;++c) {
        int n = n0 + tn*4 + c;
        int nsrc = permflag ? ((n & 3)*128 + (n >> 2)) : n;
        float v = 0.f;
        if (n < N) {
            if (ba) v += ba[nsrc];
            if (bb) v += bb[nsrc];
        }
        bias[c] = v;
    }
    #pragma unroll
    for (int r=0;r<8;++r) {
        int m = m0 + tm*8 + r;
        float v[4];
        #pragma unroll
        for (int c=0;c<4;++c) {
            float t = acc[r][c] + bias[c];
            if (expflag) t = fexp2(fminf(fmaxf(t,-40.f),40.f)*2.8853900817779268f); // e^{2t}
            v[c] = t;
        }
        int n = n0 + tn*4;
        if (n + 3 < N) {
            float4 st; st.x=v[0]; st.y=v[1]; st.z=v[2]; st.w=v[3];
            *(float4*)&C[(size_t)m*ldc + n] = st;
        } else {
            #pragma unroll
            for (int c=0;c<4;++c) if (n+c < N) C[(size_t)m*ldc + n + c] = v[c];
        }
    }
}

// ---------------- LSTM: one block per (b, dir), quarter-k f16 + split w-stream -----------
// Thread t: q=t&3 (k in [32q,32q+32)), gc=(t>>2)&3 (code 0=i,1=cell,2=f,3=o), rp=t>>4.
// Thread covers 4 rows x 32 k in f16 (64 uints): row 0 (16 uints) is preloaded into LDS
// once and re-read per step (4 ds_read_b128, lane-stride-16B balanced layout); rows 1-3
// (48 uints) stay in the L2 remat stream the allocator insists on (rounds 2-9) -- the two
// streams overlap, and h-reads are only 4 b128/thread (64 B f16 quarter), fixing round 9's
// LDS-pipe bound (16 bcast b128 = ~1536 cy/step).
// Combine: k-quarters via shfl_xor(1,2); gates via 2 ds_swizzle (xor4,xor8) -- round 8's
// verified routing. h double-buffered f16 (quarter stride 64 B -> 2-way LDS alias = free).
__global__ __launch_bounds__(512, 2)
void lstm_kernel(
    const float* __restrict__ xp,      // [dir][2048][512] permuted cols (col 4r+g, g=pytorch gate)
    const unsigned* wpk,               // [2][512][64] f16 pairs, thread-native (no __restrict)
    float* hcat)                       // [16][128][256] fp32, no __restrict
{
    const int b = blockIdx.x & 15;
    const int dir = blockIdx.x >> 4;
    const int t = threadIdx.x;
    const int q  = t & 3;
    const int gc = (t >> 2) & 3;
    const int rp = t >> 4;
    const int wave = t >> 6, lane = t & 63;
    const int G = (gc == 0) ? 0 : (gc == 1) ? 2 : (gc == 2) ? 1 : 3;
    // sigmoid for i,f,o; tanh form for cell
    const float kexp = (gc == 1) ? 2.8853900817779268f : -1.4426950408889634f;
    const float mA   = (gc == 1) ? -2.f : 1.f;
    const float mB   = (gc == 1) ?  1.f : 0.f;

    __shared__ uint4 wlds4[2048];              // 32 KB: row-0 weights, [wave*4+i][lane]
    __shared__ _Float16 h_lds[2][128];

    const unsigned* wr = wpk + ((size_t)dir*512 + t)*64;
    {   // preload row 0 (j 0..15) to LDS, lane-stride-16B (balanced banks)
        #pragma unroll
        for (int i = 0; i < 4; ++i)
            wlds4[(wave*4 + i)*64 + lane] = *(const uint4*)(wr + 4*i);
    }
    // rows 1-3: load to regs; allocator will remat into the loop = the L2 stream (intended)
    uint4 u1[4], u2[4], u3[4];
    #pragma unroll
    for (int i = 0; i < 4; ++i) {
        u1[i] = *(const uint4*)(wr + 16 + 4*i);
        u2[i] = *(const uint4*)(wr + 32 + 4*i);
        u3[i] = *(const uint4*)(wr + 48 + 4*i);
    }

    float c = 0.f;
    if (t < 128) h_lds[0][t] = (_Float16)0.f;
    __syncthreads();

    const float* xpd = xp + (size_t)dir*(2048*512) + (size_t)b*(128*512);
    const int myrow = 4*rp + q;                // row this lane owns post-combine
    const int mycol = 4*myrow + G;             // xp permuted column
    float xpv = xpd[(dir ? 127 : 0)*512 + mycol];

    for (int s = 0; s < 128; ++s) {
        const int ts = dir ? (127 - s) : s;
        const int tsn = dir ? (126 - s < 0 ? 0 : 126 - s) : (s + 1 > 127 ? 127 : s + 1);
        float xnext = xpd[tsn*512 + mycol];
        // h quarter: halfs [32q, 32q+32) = 4 uint4
        const uint4* hb = (const uint4*)&h_lds[s & 1][0];
        uint4 hv[4];
        #pragma unroll
        for (int i = 0; i < 4; ++i) hv[i] = hb[q*4 + i];
        float d0 = 0.f, d1 = 0.f, d2 = 0.f, d3 = 0.f;
        #pragma unroll
        for (int i = 0; i < 4; ++i) {
            uint4 wl = wlds4[(wave*4 + i)*64 + lane];
            d0 = dotu4(wl,    hv[i], d0);
            d1 = dotu4(u1[i], hv[i], d1);
            d2 = dotu4(u2[i], hv[i], d2);
            d3 = dotu4(u3[i], hv[i], d3);
        }
        // k-combine over q bits (lane xor 1,2 -> quad_perm DPP)
        d0 += __shfl_xor(d0, 1, 64); d1 += __shfl_xor(d1, 1, 64);
        d2 += __shfl_xor(d2, 1, 64); d3 += __shfl_xor(d3, 1, 64);
        d0 += __shfl_xor(d0, 2, 64); d1 += __shfl_xor(d1, 2, 64);
        d2 += __shfl_xor(d2, 2, 64); d3 += __shfl_xor(d3, 2, 64);
        float dsel = (q & 2) ? ((q & 1) ? d3 : d2) : ((q & 1) ? d1 : d0);
        float dot = xpv + dsel;
        float act = fmaf(mA, frcp(1.f + fexp2(kexp*dot)), mB);
        // gate combine (round-8 verified routing)
        float o1 = __uint_as_float(__builtin_amdgcn_ds_swizzle(__float_as_uint(act), 0x101F)); // xor4
        float v1 = (gc < 2) ? act * o1 : ((gc == 2) ? act : o1);
        float o2 = __uint_as_float(__builtin_amdgcn_ds_swizzle(__float_as_uint(v1), 0x201F));  // xor8
        float Af = (gc < 2) ? o2 : ((gc == 2) ? act : o1);   // sigma_f on every lane
        float Bf = (gc < 2) ? v1 : o2;                       // P on every lane
        c = fmaf(Af, c, Bf);
        float th = tanh_(c);
        float sigo = (gc == 2) ? o1 : act;                   // valid on gc 2,3
        float h = sigo * th;
        if (gc == 2) {
            h_lds[(s & 1) ^ 1][myrow] = (_Float16)h;
            hcat[((size_t)b*128 + ts)*256 + dir*128 + myrow] = h;
        }
        xpv = xnext;
        __syncthreads();
    }
}

// ------------- pairwise scorer: out[(i*128+j)*16+b] = S + sum_k w2_k / (ea_ik*eb_jk + 1) ----
// w2[k] = -2*fc2_w[k], S = sum(fc2_w)+fc2_b computed in-block (prep fused).
__global__ __launch_bounds__(256) void pair_kernel(
    const float* __restrict__ ea, const float* __restrict__ eb,
    const float* __restrict__ fc2w, const float* __restrict__ fc2b,
    float* __restrict__ out)
{
    __shared__ float eas[32][100];
    __shared__ float ebs[32][100];
    __shared__ float w2s[100];
    __shared__ float red[128];
    const int it = blockIdx.x * 32, jt = blockIdx.y * 32, b = blockIdx.z;
    const int tx = threadIdx.x;
    const float* eab = ea + (size_t)b*12800;
    const float* ebb = eb + (size_t)b*12800;
    for (int idx = tx; idx < 3200; idx += 256) {
        int r = idx / 100;
        int cc = idx - r*100;
        eas[r][cc] = eab[(it + r)*100 + cc];
        ebs[r][cc] = ebb[(jt + r)*100 + cc];
    }
    if (tx < 128) {
        float wv = (tx < 100) ? fc2w[tx] : 0.f;
        if (tx < 100) w2s[tx] = -2.f*wv;
        red[tx] = wv;
    }
    __syncthreads();
    for (int s2 = 64; s2 > 0; s2 >>= 1) {
        if (tx < s2) red[tx] += red[tx+s2];
        __syncthreads();
    }
    const float S = red[0] + fc2b[0];
    const int jp = tx & 15, ip = tx >> 4;
    const int i0 = ip*2, j0 = jp*2;
    float acc00=S, acc01=S, acc10=S, acc11=S;
    #pragma unroll
    for (int k = 0; k < 100; k += 4) {
        float4 A0 = *(const float4*)&eas[i0][k];
        float4 A1 = *(const float4*)&eas[i0+1][k];
        float4 B0 = *(const float4*)&ebs[j0][k];
        float4 B1 = *(const float4*)&ebs[j0+1][k];
        float4 W  = *(const float4*)&w2s[k];
        acc00 = fmaf(W.x, frcp(fmaf(A0.x,B0.x,1.f)), acc00);
        acc01 = fmaf(W.x, frcp(fmaf(A0.x,B1.x,1.f)), acc01);
        acc10 = fmaf(W.x, frcp(fmaf(A1.x,B0.x,1.f)), acc10);
        acc11 = fmaf(W.x, frcp(fmaf(A1.x,B1.x,1.f)), acc11);
        acc00 = fmaf(W.y, frcp(fmaf(A0.y,B0.y,1.f)), acc00);
        acc01 = fmaf(W.y, frcp(fmaf(A0.y,B1.y,1.f)), acc01);
        acc10 = fmaf(W.y, frcp(fmaf(A1.y,B0.y,1.f)), acc10);
        acc11 = fmaf(W.y, frcp(fmaf(A1.y,B1.y,1.f)), acc11);
        acc00 = fmaf(W.z, frcp(fmaf(A0.z,B0.z,1.f)), acc00);
        acc01 = fmaf(W.z, frcp(fmaf(A0.z,B1.z,1.f)), acc01);
        acc10 = fmaf(W.z, frcp(fmaf(A1.z,B0.z,1.f)), acc10);
        acc11 = fmaf(W.z, frcp(fmaf(A1.z,B1.z,1.f)), acc11);
        acc00 = fmaf(W.w, frcp(fmaf(A0.w,B0.w,1.f)), acc00);
        acc01 = fmaf(W.w, frcp(fmaf(A0.w,B1.w,1.f)), acc01);
        acc10 = fmaf(W.w, frcp(fmaf(A1.w,B0.w,1.f)), acc10);
        acc11 = fmaf(W.w, frcp(fmaf(A1.w,B1.w,1.f)), acc11);
    }
    const int gi0 = it + i0, gj0 = jt + j0;
    out[((size_t)(gi0  )*128 + gj0  )*16 + b] = acc00;
    out[((size_t)(gi0  )*128 + gj0+1)*16 + b] = acc01;
    out[((size_t)(gi0+1)*128 + gj0  )*16 + b] = acc10;
    out[((size_t)(gi0+1)*128 + gj0+1)*16 + b] = acc11;
}

extern "C" void kernel_launch(void* const* d_in, const int* in_sizes, int n_in,
                              void* d_out, int out_size, void* d_ws, size_t ws_size,
                              hipStream_t stream)
{
    (void)in_sizes; (void)n_in; (void)out_size; (void)ws_size;
    const int*   widx = (const int*)d_in[0];
    const int*   pidx = (const int*)d_in[1];
    const float* wemb = (const float*)d_in[4];
    const float* temb = (const float*)d_in[5];
    const float* w_ih_l0f = (const float*)d_in[6];
    const float* w_hh_l0f = (const float*)d_in[7];
    const float* b_ih_l0f = (const float*)d_in[8];
    const float* b_hh_l0f = (const float*)d_in[9];
    const float* w_ih_l0b = (const float*)d_in[10];
    const float* w_hh_l0b = (const float*)d_in[11];
    const float* b_ih_l0b = (const float*)d_in[12];
    const float* b_hh_l0b = (const float*)d_in[13];
    const float* w_ih_l1f = (const float*)d_in[14];
    const float* w_hh_l1f = (const float*)d_in[15];
    const float* b_ih_l1f = (const float*)d_in[16];
    const float* b_hh_l1f = (const float*)d_in[17];
    const float* w_ih_l1b = (const float*)d_in[18];
    const float* w_hh_l1b = (const float*)d_in[19];
    const float* b_ih_l1b = (const float*)d_in[20];
    const float* b_hh_l1b = (const float*)d_in[21];
    const float* fc1_w = (const float*)d_in[22];
    const float* fc1_b = (const float*)d_in[23];
    const float* fc2_w = (const float*)d_in[24];
    const float* fc2_b = (const float*)d_in[25];

    float* ws  = (float*)d_ws;
    float* x   = ws;                  // 262144
    float* xp0 = x + 262144;          // 2 * 1048576
    float* h1  = xp0 + 2097152;       // 524288
    float* xp1 = h1 + 524288;         // 2 * 1048576
    float* h2  = xp1 + 2097152;       // 524288
    float* ea  = h2 + 524288;         // 204800
    float* eb  = ea + 204800;         // 204800
    unsigned* wpk0 = (unsigned*)(eb + 204800);   // 65536 uints (layer0 f16 weights)
    unsigned* wpk1 = wpk0 + 65536;               // 65536 uints (layer1)
    // total ~6.1M floats ~= 24.5 MB

    embed_kernel<<<1024, 256, 0, stream>>>(widx, pidx, wemb, temb, x);
    pack_kernel<<<512, 256, 0, stream>>>(w_hh_l0f, w_hh_l0b, w_hh_l1f, w_hh_l1b, wpk0, wpk1);
    // layer 0 input projections (both dirs in grid.z), gate-permuted columns
    gemm_kernel<<<dim3(16,8,2), 256, 0, stream>>>(x, 128,
        w_ih_l0f, w_ih_l0b, 128,
        b_ih_l0f, b_hh_l0f, b_ih_l0b, b_hh_l0b,
        xp0, xp0 + 1048576, 512, 512, 0, 1);
    lstm_kernel<<<32, 512, 0, stream>>>(xp0, wpk0, h1);
    // layer 1 input projections, gate-permuted columns
    gemm_kernel<<<dim3(16,8,2), 256, 0, stream>>>(h1, 256,
        w_ih_l1f, w_ih_l1b, 256,
        b_ih_l1f, b_hh_l1f, b_ih_l1b, b_hh_l1b,
        xp1, xp1 + 1048576, 512, 512, 0, 1);
    lstm_kernel<<<32, 512, 0, stream>>>(xp1, wpk1, h2);
    // fc1: a = h2@wa^T -> ea = exp(2a); bp = h2@wb^T + fc1_b -> eb = exp(2bp)
    gemm_kernel<<<dim3(16,2,2), 256, 0, stream>>>(h2, 256,
        fc1_w, fc1_w + 256, 512,
        nullptr, nullptr, fc1_b, nullptr,
        ea, eb, 100, 100, 1, 0);
    pair_kernel<<<dim3(4,4,16), 256, 0, stream>>>(ea, eb, fc2_w, fc2_b, (float*)d_out);
}